// Round 10
// baseline (2025.165 us; speedup 1.0000x reference)
//
#include <hip/hip_runtime.h>

#define NN 50000
#define NE 1600000
#define RR 20
#define BN_EPS 1e-5f
#define KK (21 * 64)                   /* 1344: 20 rels + root */
#define SCAN_NB ((NN + 1023) / 1024)   /* 49 */

typedef __attribute__((ext_vector_type(8))) short bf16x8;
typedef __attribute__((ext_vector_type(4))) float f32x4;

__device__ __forceinline__ unsigned short f2bf(float f) {
    unsigned u = __float_as_uint(f);
    u += 0x7fff + ((u >> 16) & 1);        // RNE
    return (unsigned short)(u >> 16);
}
__device__ __forceinline__ void unpack8(uint4 r, float* v) {
    v[0] = __uint_as_float(r.x << 16); v[1] = __uint_as_float(r.x & 0xffff0000u);
    v[2] = __uint_as_float(r.y << 16); v[3] = __uint_as_float(r.y & 0xffff0000u);
    v[4] = __uint_as_float(r.z << 16); v[5] = __uint_as_float(r.z & 0xffff0000u);
    v[6] = __uint_as_float(r.w << 16); v[7] = __uint_as_float(r.w & 0xffff0000u);
}

// ---------------- (dst,rel) histogram (for inv_cnt) ----------------
__global__ void count_kernel(const int* __restrict__ dst, const int* __restrict__ et,
                             int* __restrict__ cnt) {
    int stride = gridDim.x * blockDim.x;
    for (int e = blockIdx.x * blockDim.x + threadIdx.x; e < NE; e += stride)
        atomicAdd(&cnt[dst[e] * RR + et[e]], 1);
}

__global__ void deg_kernel(const int* __restrict__ cnt, int* __restrict__ deg) {
    int stride = gridDim.x * blockDim.x;
    for (int n = blockIdx.x * blockDim.x + threadIdx.x; n < NN; n += stride) {
        int s = 0;
        #pragma unroll
        for (int r = 0; r < RR; ++r) s += cnt[n * RR + r];
        deg[n] = s;
    }
}

// ---------------- exclusive scan over NN entries ----------------
__global__ __launch_bounds__(256) void scan1_kernel(const int* __restrict__ in,
                                                    int* __restrict__ out,
                                                    int* __restrict__ bsums, int n) {
    __shared__ int lds[256];
    int tid  = threadIdx.x;
    int base = blockIdx.x * 1024 + tid * 4;
    int v[4];
    #pragma unroll
    for (int j = 0; j < 4; ++j) v[j] = (base + j < n) ? in[base + j] : 0;
    int tsum = v[0] + v[1] + v[2] + v[3];
    lds[tid] = tsum;
    __syncthreads();
    for (int off = 1; off < 256; off <<= 1) {
        int t = (tid >= off) ? lds[tid - off] : 0;
        __syncthreads();
        lds[tid] += t;
        __syncthreads();
    }
    int run = lds[tid] - tsum;
    #pragma unroll
    for (int j = 0; j < 4; ++j) {
        if (base + j < n) out[base + j] = run;
        run += v[j];
    }
    if (tid == 255) bsums[blockIdx.x] = lds[255];
}

__global__ __launch_bounds__(1024) void scan_top_kernel(int* __restrict__ bsums, int nb) {
    __shared__ int lds[1024];
    int tid = threadIdx.x;
    int v = (tid < nb) ? bsums[tid] : 0;
    lds[tid] = v;
    __syncthreads();
    for (int off = 1; off < 1024; off <<= 1) {
        int t = (tid >= off) ? lds[tid - off] : 0;
        __syncthreads();
        lds[tid] += t;
        __syncthreads();
    }
    bsums[tid] = lds[tid] - v;
}

__global__ void scan_add_kernel(int* __restrict__ out, const int* __restrict__ bsums, int n) {
    int stride = gridDim.x * blockDim.x;
    int i = blockIdx.x * blockDim.x + threadIdx.x;
    if (i == 0) out[NN] = NE;
    for (; i < n; i += stride)
        out[i] += bsums[i >> 10];
}

// ------- bucket-fill: ep = {src | rel<<20, inv_cnt}, grouped by dst ----------
__global__ void fill_kernel(const int* __restrict__ src, const int* __restrict__ dst,
                            const int* __restrict__ et, const int* __restrict__ offs,
                            const int* __restrict__ cntdr,
                            int* __restrict__ fill, uint2* __restrict__ ep) {
    int stride = gridDim.x * blockDim.x;
    for (int e = blockIdx.x * blockDim.x + threadIdx.x; e < NE; e += stride) {
        int d = dst[e], r = et[e];
        int pos = offs[d] + atomicAdd(&fill[d], 1);
        int c = cntdr[d * RR + r];
        float ic = 1.0f / (float)(c > 0 ? c : 1);
        ep[pos] = make_uint2((unsigned)src[e] | ((unsigned)r << 20),
                             __float_as_uint(ic));
    }
}

// ------- weight prep: Wg[l][n][k] bf16, k = r*64 + i (r=20 is root): Wg[n][k]=W_r[i][n]
__global__ __launch_bounds__(256) void wprep_kernel(const float* __restrict__ Wh,
                                                    const float* __restrict__ rooth,
                                                    unsigned short* __restrict__ Wg) {
    int l = blockIdx.x / 21, r = blockIdx.x % 21;
    const float* Ws = (r < 20) ? Wh + ((size_t)l * 20 + r) * 4096
                               : rooth + (size_t)l * 4096;
    unsigned short* Wd = Wg + (size_t)l * 64 * KK + r * 64;
    int t = threadIdx.x;
    int n4 = (t & 15) * 4;
    for (int k = t >> 4; k < 64; k += 16) {
        float4 w = *(const float4*)&Ws[(size_t)k * 64 + n4];
        Wd[(size_t)(n4 + 0) * KK + k] = f2bf(w.x);
        Wd[(size_t)(n4 + 1) * KK + k] = f2bf(w.y);
        Wd[(size_t)(n4 + 2) * KK + k] = f2bf(w.z);
        Wd[(size_t)(n4 + 3) * KK + k] = f2bf(w.w);
    }
}

// -------- layer 0 fused: gather x[src], inline 4->64 transform, mean+root+BN --------
__global__ __launch_bounds__(256) void agg0_kernel(
    const float* __restrict__ x, const int* __restrict__ offs,
    const uint2* __restrict__ ep,
    const float* __restrict__ W0, const float* __restrict__ root0,
    const float* __restrict__ b0, const float* __restrict__ gamma,
    const float* __restrict__ beta, const float* __restrict__ rmean,
    const float* __restrict__ rvar, unsigned short* __restrict__ outb) {
    __shared__ float Wl[21 * 256];
    int tid = threadIdx.x;
    for (int i = tid; i < 21 * 256; i += 256)
        Wl[i] = (i < 20 * 256) ? W0[i] : root0[i - 20 * 256];
    __syncthreads();

    int wid   = (blockIdx.x * 256 + tid) >> 6;
    int nw    = (gridDim.x * 256) >> 6;
    int lane  = tid & 63;
    int eslot = lane >> 3;
    int flane = lane & 7;

    for (int n = wid; n < NN; n += nw) {
        int e0 = offs[n], e1 = offs[n + 1];
        float a[8] = {0, 0, 0, 0, 0, 0, 0, 0};
        for (int e = e0 + eslot; e < e1; e += 8) {
            uint2 m = ep[e];
            float ic = __uint_as_float(m.y);
            float4 xv = *(const float4*)&x[(size_t)(m.x & 0xFFFFF) * 4];
            const float* w = &Wl[(m.x >> 20) * 256 + flane * 8];
            float4 w0 = *(const float4*)&w[0],   w0b = *(const float4*)&w[4];
            float4 w1 = *(const float4*)&w[64],  w1b = *(const float4*)&w[68];
            float4 w2 = *(const float4*)&w[128], w2b = *(const float4*)&w[132];
            float4 w3 = *(const float4*)&w[192], w3b = *(const float4*)&w[196];
            a[0] += ic * (xv.x * w0.x + xv.y * w1.x + xv.z * w2.x + xv.w * w3.x);
            a[1] += ic * (xv.x * w0.y + xv.y * w1.y + xv.z * w2.y + xv.w * w3.y);
            a[2] += ic * (xv.x * w0.z + xv.y * w1.z + xv.z * w2.z + xv.w * w3.z);
            a[3] += ic * (xv.x * w0.w + xv.y * w1.w + xv.z * w2.w + xv.w * w3.w);
            a[4] += ic * (xv.x * w0b.x + xv.y * w1b.x + xv.z * w2b.x + xv.w * w3b.x);
            a[5] += ic * (xv.x * w0b.y + xv.y * w1b.y + xv.z * w2b.y + xv.w * w3b.y);
            a[6] += ic * (xv.x * w0b.z + xv.y * w1b.z + xv.z * w2b.z + xv.w * w3b.z);
            a[7] += ic * (xv.x * w0b.w + xv.y * w1b.w + xv.z * w2b.w + xv.w * w3b.w);
        }
        #pragma unroll
        for (int off = 8; off < 64; off <<= 1)
            #pragma unroll
            for (int j = 0; j < 8; ++j) a[j] += __shfl_xor(a[j], off);

        if (eslot == 0) {
            float4 xn = *(const float4*)&x[(size_t)n * 4];
            const float* w = &Wl[20 * 256 + flane * 8];
            float v[8];
            #pragma unroll
            for (int j = 0; j < 8; ++j) {
                a[j] += xn.x * w[j] + xn.y * w[64 + j] + xn.z * w[128 + j] + xn.w * w[192 + j];
                int col = flane * 8 + j;
                float s = gamma[col] * rsqrtf(rvar[col] + BN_EPS);
                v[j] = (a[j] + b0[col] - rmean[col]) * s + beta[col];
            }
            ushort4 p0, p1;
            p0.x = f2bf(v[0]); p0.y = f2bf(v[1]); p0.z = f2bf(v[2]); p0.w = f2bf(v[3]);
            p1.x = f2bf(v[4]); p1.y = f2bf(v[5]); p1.z = f2bf(v[6]); p1.w = f2bf(v[7]);
            *(ushort4*)&outb[(size_t)n * 64 + flane * 8]     = p0;
            *(ushort4*)&outb[(size_t)n * 64 + flane * 8 + 4] = p1;
        }
    }
}

// ---------- msum build: msum[n][r][:] = sum ic*h[src] (fp32 LDS) ; item 20 = h[n] ----
__global__ __launch_bounds__(256) void msum_kernel(
    const unsigned short* __restrict__ hin, const int* __restrict__ offs,
    const uint2* __restrict__ ep, unsigned short* __restrict__ msum) {
    constexpr int RP = 68;               // padded row stride (f32)
    __shared__ float acc[4][20 * RP];    // 4 waves x 5440 B
    const int tid   = threadIdx.x;
    const int wv    = tid >> 6;
    const int lane  = tid & 63;
    const int wid   = (blockIdx.x * 256 + tid) >> 6;
    const int nw    = (gridDim.x * 256) >> 6;
    const int eslot = lane >> 3;
    const int flane = lane & 7;
    float* A = acc[wv];

    for (int n = wid; n < NN; n += nw) {
        float4 z4 = make_float4(0.f, 0.f, 0.f, 0.f);
        #pragma unroll
        for (int i = 0; i < 6; ++i) {
            int idx = i * 64 + lane;
            if (idx < 340) ((float4*)A)[idx] = z4;
        }
        int e0 = offs[n], e1 = offs[n + 1];
        for (int e = e0 + eslot; e < e1; e += 8) {
            uint2 m = ep[e];
            float ic = __uint_as_float(m.y);
            int s = m.x & 0xFFFFF;
            int r = m.x >> 20;
            uint4 row = *(const uint4*)&hin[(size_t)s * 64 + flane * 8];
            float v[8]; unpack8(row, v);
            float* p = &A[r * RP + flane * 8];
            #pragma unroll
            for (int j = 0; j < 8; ++j) atomicAdd(p + j, ic * v[j]);
        }
        unsigned* out = (unsigned*)&msum[(size_t)n * KK];
        #pragma unroll
        for (int i = 0; i < 10; ++i) {
            int idx = i * 64 + lane;                 // 0..639
            int idx2 = idx * 2;
            int r = idx2 >> 6, f = idx2 & 63;
            float lo = A[r * RP + f], hi = A[r * RP + f + 1];
            out[idx] = (unsigned)f2bf(lo) | ((unsigned)f2bf(hi) << 16);
        }
        if (lane < 32)
            out[640 + lane] = ((const unsigned*)&hin[(size_t)n * 64])[lane];
    }
}

// ---------- dense GEMM: out[n][:] = msum[n][0..1344] @ Wg[1344][64] + BN (+ReLU) -----
// 64-node tile, 4 waves. Staging: srow=tid>>3 (0..31, two halves), sch=tid&7 -> full
// 64x64 tile coverage (512 uint4 per tile). FIX of round 9's half-tile staging bug.
template <bool LAST>
__global__ __launch_bounds__(256) void gemm_kernel(
    const unsigned short* __restrict__ msum, const unsigned short* __restrict__ Wg,
    const float* __restrict__ bias, const float* __restrict__ gamma,
    const float* __restrict__ beta, const float* __restrict__ rmean,
    const float* __restrict__ rvar, unsigned short* __restrict__ outb,
    float* __restrict__ outf) {
    __shared__ unsigned short stage[2][64 * 72];   // A, B tiles (and epilogue staging)
    unsigned short* Al = stage[0];
    unsigned short* Bl = stage[1];
    const int tid  = threadIdx.x;
    const int wv   = tid >> 6;
    const int lane = tid & 63;
    const int frow = lane & 15;
    const int kgrp = lane >> 4;
    const int n0   = blockIdx.x * 64;

    f32x4 acc[4];
    #pragma unroll
    for (int cb = 0; cb < 4; ++cb) acc[cb] = (f32x4){0.f, 0.f, 0.f, 0.f};

    const int srow = tid >> 3;        // 0..31
    const int sch  = tid & 7;         // 0..7: 8 chunks x 8 shorts = 64 k
    const int gnA0 = min(n0 + srow, NN - 1);
    const int gnA1 = min(n0 + srow + 32, NN - 1);

    for (int k0 = 0; k0 < KK; k0 += 64) {
        __syncthreads();
        *(uint4*)&Al[srow * 72 + sch * 8] =
            *(const uint4*)&msum[(size_t)gnA0 * KK + k0 + sch * 8];
        *(uint4*)&Al[(srow + 32) * 72 + sch * 8] =
            *(const uint4*)&msum[(size_t)gnA1 * KK + k0 + sch * 8];
        *(uint4*)&Bl[srow * 72 + sch * 8] =
            *(const uint4*)&Wg[(size_t)srow * KK + k0 + sch * 8];
        *(uint4*)&Bl[(srow + 32) * 72 + sch * 8] =
            *(const uint4*)&Wg[(size_t)(srow + 32) * KK + k0 + sch * 8];
        __syncthreads();
        #pragma unroll
        for (int ks = 0; ks < 2; ++ks) {
            bf16x8 a = *(bf16x8*)&Al[(wv * 16 + frow) * 72 + ks * 32 + kgrp * 8];
            #pragma unroll
            for (int cb = 0; cb < 4; ++cb) {
                bf16x8 b = *(bf16x8*)&Bl[(cb * 16 + frow) * 72 + ks * 32 + kgrp * 8];
                acc[cb] = __builtin_amdgcn_mfma_f32_16x16x32_bf16(a, b, acc[cb], 0, 0, 0);
            }
        }
    }

    // epilogue: D row = wv*16 + kgrp*4 + j, col = cb*16 + frow; bias+BN (+ReLU)
    __syncthreads();
    #pragma unroll
    for (int cb = 0; cb < 4; ++cb) {
        int col = cb * 16 + frow;
        float s  = gamma[col] * rsqrtf(rvar[col] + BN_EPS);
        float sh = beta[col] - rmean[col] * s;
        float bi = bias[col];
        #pragma unroll
        for (int j = 0; j < 4; ++j) {
            float v = (acc[cb][j] + bi) * s + sh;
            int row = wv * 16 + kgrp * 4 + j;
            if (LAST) ((float*)stage)[row * 72 + col] = fmaxf(v, 0.f);
            else      Al[row * 72 + col] = f2bf(v);
        }
    }
    __syncthreads();
    if (LAST) {
        const float* F = (const float*)stage;
        #pragma unroll
        for (int i = tid; i < 1024; i += 256) {
            int row = i >> 4, c4 = i & 15;
            int node = n0 + row;
            if (node < NN)
                *(float4*)&outf[(size_t)node * 64 + c4 * 4] =
                    *(const float4*)&F[row * 72 + c4 * 4];
        }
    } else {
        #pragma unroll
        for (int i = tid; i < 512; i += 256) {
            int row = i >> 3, c8 = i & 7;
            int node = n0 + row;
            if (node < NN)
                *(uint4*)&outb[(size_t)node * 64 + c8 * 8] =
                    *(const uint4*)&Al[row * 72 + c8 * 8];
        }
    }
}

extern "C" void kernel_launch(void* const* d_in, const int* in_sizes, int n_in,
                              void* d_out, int out_size, void* d_ws, size_t ws_size,
                              hipStream_t stream) {
    const float* x     = (const float*)d_in[0];
    const int*   ei    = (const int*)d_in[1];
    const int*   et    = (const int*)d_in[2];
    const float* W0    = (const float*)d_in[3];
    const float* root0 = (const float*)d_in[4];
    const float* b0    = (const float*)d_in[5];
    const float* Wh    = (const float*)d_in[6];
    const float* rooth = (const float*)d_in[7];
    const float* bh    = (const float*)d_in[8];
    const float* gamma = (const float*)d_in[9];
    const float* beta  = (const float*)d_in[10];
    const float* rmean = (const float*)d_in[11];
    const float* rvar  = (const float*)d_in[12];
    float* out = (float*)d_out;

    const int* src = ei;
    const int* dst = ei + NE;

    // workspace (~165 MB; round 7/8 confirmed this fits: npass was 1)
    int*   cntdr = (int*)d_ws;                        // 1,000,000
    int*   deg   = cntdr + 1000000;                   // 50,000
    int*   fill  = deg + 50000;                       // 50,000
    int*   offs  = fill + 50000;                      // 50,004
    int*   bsums = offs + 50004;                      // 1,024
    uint2* ep    = (uint2*)(bsums + 1024);            // NE x 8B
    unsigned short* Wg = (unsigned short*)(ep + NE);  // 3*64*1344
    unsigned short* h0 = Wg + 3 * 64 * KK;            // N*64
    unsigned short* h1 = h0 + NN * 64;                // N*64
    unsigned short* msum = h1 + NN * 64;              // N*1344 = 134.4 MB

    // ---- CSR build ----
    hipMemsetAsync(cntdr, 0, (size_t)NN * RR * sizeof(int), stream);
    hipMemsetAsync(fill, 0, (size_t)NN * sizeof(int), stream);
    count_kernel<<<2048, 256, 0, stream>>>(dst, et, cntdr);
    deg_kernel<<<256, 256, 0, stream>>>(cntdr, deg);
    scan1_kernel<<<SCAN_NB, 256, 0, stream>>>(deg, offs, bsums, NN);
    scan_top_kernel<<<1, 1024, 0, stream>>>(bsums, SCAN_NB);
    scan_add_kernel<<<256, 256, 0, stream>>>(offs, bsums, NN);
    fill_kernel<<<2048, 256, 0, stream>>>(src, dst, et, offs, cntdr, fill, ep);
    wprep_kernel<<<63, 256, 0, stream>>>(Wh, rooth, Wg);

    // ---- layer 0: fully fused ----
    agg0_kernel<<<2048, 256, 0, stream>>>(
        x, offs, ep, W0, root0, b0, gamma, beta, rmean, rvar, h0);

    // ---- layers 1..3: msum build + dense GEMM (BN fused) ----
    const int GB = (NN + 63) / 64;   // 782
    for (int l = 1; l < 4; ++l) {
        const unsigned short* hin = (l == 2) ? h1 : h0;
        unsigned short* hout = (l == 1) ? h1 : h0;
        const float* bl  = bh + (size_t)(l - 1) * 64;
        const float* gl  = gamma + (size_t)l * 64;
        const float* btl = beta + (size_t)l * 64;
        const float* rml = rmean + (size_t)l * 64;
        const float* rvl = rvar + (size_t)l * 64;
        const unsigned short* WgL = Wg + (size_t)(l - 1) * 64 * KK;
        msum_kernel<<<2048, 256, 0, stream>>>(hin, offs, ep, msum);
        if (l == 3)
            gemm_kernel<true><<<GB, 256, 0, stream>>>(
                msum, WgL, bl, gl, btl, rml, rvl, nullptr, out);
        else
            gemm_kernel<false><<<GB, 256, 0, stream>>>(
                msum, WgL, bl, gl, btl, rml, rvl, hout, nullptr);
    }
}

// Round 11
// 726.044 us; speedup vs baseline: 2.7893x; 2.7893x over previous
//
#include <hip/hip_runtime.h>

#define NN 50000
#define NE 1600000
#define RR 20
#define BN_EPS 1e-5f
#define SCAN_NB ((NN + 1023) / 1024)   /* 49 */

typedef __attribute__((ext_vector_type(8))) short bf16x8;
typedef __attribute__((ext_vector_type(4))) float f32x4;

__device__ __forceinline__ unsigned short f2bf(float f) {
    unsigned u = __float_as_uint(f);
    u += 0x7fff + ((u >> 16) & 1);        // RNE
    return (unsigned short)(u >> 16);
}
__device__ __forceinline__ void unpack8(uint4 r, float* v) {
    v[0] = __uint_as_float(r.x << 16); v[1] = __uint_as_float(r.x & 0xffff0000u);
    v[2] = __uint_as_float(r.y << 16); v[3] = __uint_as_float(r.y & 0xffff0000u);
    v[4] = __uint_as_float(r.z << 16); v[5] = __uint_as_float(r.z & 0xffff0000u);
    v[6] = __uint_as_float(r.w << 16); v[7] = __uint_as_float(r.w & 0xffff0000u);
}

// ---------------- per-dst degree (direct) ----------------
__global__ void deg_kernel(const int* __restrict__ dst, int* __restrict__ deg) {
    int stride = gridDim.x * blockDim.x;
    for (int e = blockIdx.x * blockDim.x + threadIdx.x; e < NE; e += stride)
        atomicAdd(&deg[dst[e]], 1);
}

// ---------------- exclusive scan over NN entries ----------------
__global__ __launch_bounds__(256) void scan1_kernel(const int* __restrict__ in,
                                                    int* __restrict__ out,
                                                    int* __restrict__ bsums, int n) {
    __shared__ int lds[256];
    int tid  = threadIdx.x;
    int base = blockIdx.x * 1024 + tid * 4;
    int v[4];
    #pragma unroll
    for (int j = 0; j < 4; ++j) v[j] = (base + j < n) ? in[base + j] : 0;
    int tsum = v[0] + v[1] + v[2] + v[3];
    lds[tid] = tsum;
    __syncthreads();
    for (int off = 1; off < 256; off <<= 1) {
        int t = (tid >= off) ? lds[tid - off] : 0;
        __syncthreads();
        lds[tid] += t;
        __syncthreads();
    }
    int run = lds[tid] - tsum;
    #pragma unroll
    for (int j = 0; j < 4; ++j) {
        if (base + j < n) out[base + j] = run;
        run += v[j];
    }
    if (tid == 255) bsums[blockIdx.x] = lds[255];
}

__global__ __launch_bounds__(1024) void scan_top_kernel(int* __restrict__ bsums, int nb) {
    __shared__ int lds[1024];
    int tid = threadIdx.x;
    int v = (tid < nb) ? bsums[tid] : 0;
    lds[tid] = v;
    __syncthreads();
    for (int off = 1; off < 1024; off <<= 1) {
        int t = (tid >= off) ? lds[tid - off] : 0;
        __syncthreads();
        lds[tid] += t;
        __syncthreads();
    }
    bsums[tid] = lds[tid] - v;
}

__global__ void scan_add_kernel(int* __restrict__ out, const int* __restrict__ bsums, int n) {
    int stride = gridDim.x * blockDim.x;
    int i = blockIdx.x * blockDim.x + threadIdx.x;
    if (i == 0) out[NN] = NE;
    for (; i < n; i += stride)
        out[i] += bsums[i >> 10];
}

// ------- bucket-fill: ep = src | rel<<20 (4B), grouped by dst ----------
__global__ void fill_kernel(const int* __restrict__ src, const int* __restrict__ dst,
                            const int* __restrict__ et, const int* __restrict__ offs,
                            int* __restrict__ fill, unsigned* __restrict__ ep) {
    int stride = gridDim.x * blockDim.x;
    for (int e = blockIdx.x * blockDim.x + threadIdx.x; e < NE; e += stride) {
        int d = dst[e];
        int pos = offs[d] + atomicAdd(&fill[d], 1);
        ep[pos] = (unsigned)src[e] | ((unsigned)et[e] << 20);
    }
}

// ------- weight prep: Wt[l][r][n][k] bf16 (n = out col, k contiguous), r=20 root -----
__global__ __launch_bounds__(256) void wprep_kernel(const float* __restrict__ Wh,
                                                    const float* __restrict__ rooth,
                                                    unsigned short* __restrict__ Wt) {
    int l = blockIdx.x / 21, r = blockIdx.x % 21;
    const float* Ws = (r < 20) ? Wh + ((size_t)l * 20 + r) * 4096
                               : rooth + (size_t)l * 4096;
    unsigned short* Wd = Wt + ((size_t)l * 21 + r) * 4096;
    int t = threadIdx.x;
    int n4 = (t & 15) * 4;
    for (int k = t >> 4; k < 64; k += 16) {
        float4 w = *(const float4*)&Ws[(size_t)k * 64 + n4];
        Wd[(n4 + 0) * 64 + k] = f2bf(w.x);
        Wd[(n4 + 1) * 64 + k] = f2bf(w.y);
        Wd[(n4 + 2) * 64 + k] = f2bf(w.z);
        Wd[(n4 + 3) * 64 + k] = f2bf(w.w);
    }
}

// -------- layer 0 fused: gather x[src], inline 4->64 transform, mean+root+BN --------
// In-wave inv_cnt: count pass into per-wave LDS [20] counters, then ic = fw[wv][r].
__global__ __launch_bounds__(256) void agg0_kernel(
    const float* __restrict__ x, const int* __restrict__ offs,
    const unsigned* __restrict__ ep,
    const float* __restrict__ W0, const float* __restrict__ root0,
    const float* __restrict__ b0, const float* __restrict__ gamma,
    const float* __restrict__ beta, const float* __restrict__ rmean,
    const float* __restrict__ rvar, unsigned short* __restrict__ outb) {
    __shared__ float Wl[21 * 256];
    __shared__ int   cw[4][24];
    __shared__ float fw[4][24];
    int tid = threadIdx.x;
    for (int i = tid; i < 21 * 256; i += 256)
        Wl[i] = (i < 20 * 256) ? W0[i] : root0[i - 20 * 256];
    __syncthreads();

    int wid   = (blockIdx.x * 256 + tid) >> 6;
    int nw    = (gridDim.x * 256) >> 6;
    int wv    = tid >> 6;
    int lane  = tid & 63;
    int eslot = lane >> 3;
    int flane = lane & 7;

    for (int n = wid; n < NN; n += nw) {
        int e0 = offs[n], e1 = offs[n + 1];
        if (lane < 20) cw[wv][lane] = 0;
        for (int e = e0 + eslot; e < e1; e += 8) {
            unsigned m = ep[e];
            if (flane == 0) atomicAdd(&cw[wv][m >> 20], 1);
        }
        if (lane < 20) {
            int c = cw[wv][lane];
            fw[wv][lane] = 1.0f / (float)(c > 0 ? c : 1);
        }
        float a[8] = {0, 0, 0, 0, 0, 0, 0, 0};
        for (int e = e0 + eslot; e < e1; e += 8) {
            unsigned m = ep[e];
            float ic = fw[wv][m >> 20];
            float4 xv = *(const float4*)&x[(size_t)(m & 0xFFFFF) * 4];
            const float* w = &Wl[(m >> 20) * 256 + flane * 8];
            float4 w0 = *(const float4*)&w[0],   w0b = *(const float4*)&w[4];
            float4 w1 = *(const float4*)&w[64],  w1b = *(const float4*)&w[68];
            float4 w2 = *(const float4*)&w[128], w2b = *(const float4*)&w[132];
            float4 w3 = *(const float4*)&w[192], w3b = *(const float4*)&w[196];
            a[0] += ic * (xv.x * w0.x + xv.y * w1.x + xv.z * w2.x + xv.w * w3.x);
            a[1] += ic * (xv.x * w0.y + xv.y * w1.y + xv.z * w2.y + xv.w * w3.y);
            a[2] += ic * (xv.x * w0.z + xv.y * w1.z + xv.z * w2.z + xv.w * w3.z);
            a[3] += ic * (xv.x * w0.w + xv.y * w1.w + xv.z * w2.w + xv.w * w3.w);
            a[4] += ic * (xv.x * w0b.x + xv.y * w1b.x + xv.z * w2b.x + xv.w * w3b.x);
            a[5] += ic * (xv.x * w0b.y + xv.y * w1b.y + xv.z * w2b.y + xv.w * w3b.y);
            a[6] += ic * (xv.x * w0b.z + xv.y * w1b.z + xv.z * w2b.z + xv.w * w3b.z);
            a[7] += ic * (xv.x * w0b.w + xv.y * w1b.w + xv.z * w2b.w + xv.w * w3b.w);
        }
        #pragma unroll
        for (int off = 8; off < 64; off <<= 1)
            #pragma unroll
            for (int j = 0; j < 8; ++j) a[j] += __shfl_xor(a[j], off);

        if (eslot == 0) {
            float4 xn = *(const float4*)&x[(size_t)n * 4];
            const float* w = &Wl[20 * 256 + flane * 8];
            float v[8];
            #pragma unroll
            for (int j = 0; j < 8; ++j) {
                a[j] += xn.x * w[j] + xn.y * w[64 + j] + xn.z * w[128 + j] + xn.w * w[192 + j];
                int col = flane * 8 + j;
                float s = gamma[col] * rsqrtf(rvar[col] + BN_EPS);
                v[j] = (a[j] + b0[col] - rmean[col]) * s + beta[col];
            }
            ushort4 p0, p1;
            p0.x = f2bf(v[0]); p0.y = f2bf(v[1]); p0.z = f2bf(v[2]); p0.w = f2bf(v[3]);
            p1.x = f2bf(v[4]); p1.y = f2bf(v[5]); p1.z = f2bf(v[6]); p1.w = f2bf(v[7]);
            *(ushort4*)&outb[(size_t)n * 64 + flane * 8]     = p0;
            *(ushort4*)&outb[(size_t)n * 64 + flane * 8 + 4] = p1;
        }
    }
}

// ---------------- hidden transform: 128-node x 3-relation blocks --------------------
// T[r][n][:] = h[n][:] @ W_item(c0+r). A-frags loaded once, reused across 3 rels.
// LDS-staged D for coalesced dwordx4 T writes.
__global__ __launch_bounds__(256) void xform_kernel(
    const unsigned short* __restrict__ hin, const unsigned short* __restrict__ WtL,
    unsigned short* __restrict__ T, int c0, int nr) {
    __shared__ unsigned short tile[128 * 72];   // 18432 B
    const int tid  = threadIdx.x;
    const int n0   = blockIdx.x * 128;
    const int rg   = blockIdx.y;                 // rel group (3 rels)
    const int wv   = tid >> 6;
    const int lane = tid & 63;
    const int frow = lane & 15;
    const int kgrp = lane >> 4;

    bf16x8 a[2][2];
    #pragma unroll
    for (int g = 0; g < 2; ++g) {
        int arc = min(n0 + wv * 32 + g * 16 + frow, NN - 1);
        a[g][0] = *(const bf16x8*)&hin[(size_t)arc * 64 + kgrp * 8];
        a[g][1] = *(const bf16x8*)&hin[(size_t)arc * 64 + 32 + kgrp * 8];
    }

    int rend = min(rg * 3 + 3, nr);
    for (int r = rg * 3; r < rend; ++r) {
        const unsigned short* Wr = WtL + (size_t)(c0 + r) * 4096;
        unsigned short* Tr = T + (size_t)r * NN * 64;
        #pragma unroll
        for (int cb = 0; cb < 4; ++cb) {
            bf16x8 b0 = *(const bf16x8*)&Wr[(cb * 16 + frow) * 64 + kgrp * 8];
            bf16x8 b1 = *(const bf16x8*)&Wr[(cb * 16 + frow) * 64 + 32 + kgrp * 8];
            #pragma unroll
            for (int g = 0; g < 2; ++g) {
                f32x4 d = {0.f, 0.f, 0.f, 0.f};
                d = __builtin_amdgcn_mfma_f32_16x16x32_bf16(a[g][0], b0, d, 0, 0, 0);
                d = __builtin_amdgcn_mfma_f32_16x16x32_bf16(a[g][1], b1, d, 0, 0, 0);
                #pragma unroll
                for (int j = 0; j < 4; ++j)
                    tile[(wv * 32 + g * 16 + kgrp * 4 + j) * 72 + cb * 16 + frow] = f2bf(d[j]);
            }
        }
        __syncthreads();
        #pragma unroll
        for (int i = tid; i < 1024; i += 256) {
            int row = i >> 3, c8 = i & 7;
            int node = n0 + row;
            if (node < NN)
                *(uint4*)&Tr[(size_t)node * 64 + c8 * 8] =
                    *(const uint4*)&tile[row * 72 + c8 * 8];
        }
        __syncthreads();
    }
}

// ---------------- aggregate: out[n] = sum_e ic*T[rel][src] (+root, +accum, +BN) -----
// One wave per node; in-wave inv_cnt via per-wave LDS counters.
template <bool FIRST, bool LASTP, bool LASTL>
__global__ __launch_bounds__(256) void agg_kernel(
    const unsigned short* __restrict__ T, const int* __restrict__ offs,
    const unsigned* __restrict__ ep, float* __restrict__ accum, int c0, int c1,
    const float* __restrict__ bias, const float* __restrict__ gamma,
    const float* __restrict__ beta, const float* __restrict__ rmean,
    const float* __restrict__ rvar, unsigned short* __restrict__ outb,
    float* __restrict__ outf) {
    constexpr bool FULL = FIRST && LASTP;
    __shared__ int   cw[4][24];
    __shared__ float fw[4][24];
    int wid   = (blockIdx.x * 256 + threadIdx.x) >> 6;
    int nw    = (gridDim.x * 256) >> 6;
    int wv    = threadIdx.x >> 6;
    int lane  = threadIdx.x & 63;
    int eslot = lane >> 3;
    int flane = lane & 7;
    const unsigned uc0 = (unsigned)c0;
    const unsigned ce  = (c1 < RR) ? (unsigned)c1 : (unsigned)RR;

    for (int n = wid; n < NN; n += nw) {
        int e0 = offs[n], e1 = offs[n + 1];
        if (lane < 20) cw[wv][lane] = 0;
        for (int e = e0 + eslot; e < e1; e += 8) {
            unsigned m = ep[e];
            if (flane == 0) atomicAdd(&cw[wv][m >> 20], 1);
        }
        if (lane < 20) {
            int c = cw[wv][lane];
            fw[wv][lane] = 1.0f / (float)(c > 0 ? c : 1);
        }
        float a[8] = {0, 0, 0, 0, 0, 0, 0, 0};
        for (int e = e0 + eslot; e < e1; e += 8) {
            unsigned m = ep[e];
            unsigned r = m >> 20;
            if (FULL || (r >= uc0 && r < ce)) {
                float ic = fw[wv][r];
                size_t ti = ((size_t)(r - uc0) * NN + (m & 0xFFFFF)) * 64;
                uint4 row = *(const uint4*)&T[ti + flane * 8];
                float v[8]; unpack8(row, v);
                #pragma unroll
                for (int j = 0; j < 8; ++j) a[j] += ic * v[j];
            }
        }
        #pragma unroll
        for (int off = 8; off < 64; off <<= 1)
            #pragma unroll
            for (int j = 0; j < 8; ++j) a[j] += __shfl_xor(a[j], off);

        if (eslot == 0) {
            if (LASTP) {   // root item (20) lives in the last chunk
                uint4 rr = *(const uint4*)&T[((size_t)(20 - uc0) * NN + n) * 64 + flane * 8];
                float rv[8]; unpack8(rr, rv);
                #pragma unroll
                for (int j = 0; j < 8; ++j) a[j] += rv[j];
            }
            if (!FIRST) {
                float4 p0 = *(const float4*)&accum[(size_t)n * 64 + flane * 8];
                float4 p1 = *(const float4*)&accum[(size_t)n * 64 + flane * 8 + 4];
                a[0] += p0.x; a[1] += p0.y; a[2] += p0.z; a[3] += p0.w;
                a[4] += p1.x; a[5] += p1.y; a[6] += p1.z; a[7] += p1.w;
            }
            if (!LASTP) {
                *(float4*)&accum[(size_t)n * 64 + flane * 8] =
                    make_float4(a[0], a[1], a[2], a[3]);
                *(float4*)&accum[(size_t)n * 64 + flane * 8 + 4] =
                    make_float4(a[4], a[5], a[6], a[7]);
            } else {
                float v[8];
                #pragma unroll
                for (int j = 0; j < 8; ++j) {
                    int col = flane * 8 + j;
                    float s = gamma[col] * rsqrtf(rvar[col] + BN_EPS);
                    v[j] = (a[j] + bias[col] - rmean[col]) * s + beta[col];
                }
                if (LASTL) {
                    float4 o0 = make_float4(fmaxf(v[0],0.f), fmaxf(v[1],0.f),
                                            fmaxf(v[2],0.f), fmaxf(v[3],0.f));
                    float4 o1 = make_float4(fmaxf(v[4],0.f), fmaxf(v[5],0.f),
                                            fmaxf(v[6],0.f), fmaxf(v[7],0.f));
                    *(float4*)&outf[(size_t)n * 64 + flane * 8]     = o0;
                    *(float4*)&outf[(size_t)n * 64 + flane * 8 + 4] = o1;
                } else {
                    ushort4 p0, p1;
                    p0.x = f2bf(v[0]); p0.y = f2bf(v[1]);
                    p0.z = f2bf(v[2]); p0.w = f2bf(v[3]);
                    p1.x = f2bf(v[4]); p1.y = f2bf(v[5]);
                    p1.z = f2bf(v[6]); p1.w = f2bf(v[7]);
                    *(ushort4*)&outb[(size_t)n * 64 + flane * 8]     = p0;
                    *(ushort4*)&outb[(size_t)n * 64 + flane * 8 + 4] = p1;
                }
            }
        }
    }
}

extern "C" void kernel_launch(void* const* d_in, const int* in_sizes, int n_in,
                              void* d_out, int out_size, void* d_ws, size_t ws_size,
                              hipStream_t stream) {
    const float* x     = (const float*)d_in[0];
    const int*   ei    = (const int*)d_in[1];
    const int*   et    = (const int*)d_in[2];
    const float* W0    = (const float*)d_in[3];
    const float* root0 = (const float*)d_in[4];
    const float* b0    = (const float*)d_in[5];
    const float* Wh    = (const float*)d_in[6];
    const float* rooth = (const float*)d_in[7];
    const float* bh    = (const float*)d_in[8];
    const float* gamma = (const float*)d_in[9];
    const float* beta  = (const float*)d_in[10];
    const float* rmean = (const float*)d_in[11];
    const float* rvar  = (const float*)d_in[12];
    float* out = (float*)d_out;

    const int* src = ei;
    const int* dst = ei + NE;

    // workspace layout (fixed ≈ 33 MB, then T up to 134.4 MB; round 7/8: npass was 1)
    int*      deg   = (int*)d_ws;                     // 50,000
    int*      fill  = deg + 50000;                    // 50,000
    int*      offs  = fill + 50000;                   // 50,004
    int*      bsums = offs + 50004;                   // 1,024
    unsigned* ep    = (unsigned*)(bsums + 1024);      // NE x 4B
    unsigned short* Wt = (unsigned short*)(ep + NE);  // 3*21*4096
    unsigned short* h0 = Wt + 3 * 21 * 4096;          // N*64
    unsigned short* h1 = h0 + NN * 64;                // N*64
    float* accum = (float*)(h1 + NN * 64);            // N*64 fp32
    unsigned short* T = (unsigned short*)(accum + NN * 64);

    size_t used  = (size_t)((char*)T - (char*)d_ws);
    size_t avail = (ws_size > used) ? ws_size - used : 0;
    size_t per   = (size_t)NN * 64 * 2;
    int nrel = (int)(avail / per);
    if (nrel < 1) nrel = 1;
    if (nrel > 21) nrel = 21;
    int npass = (21 + nrel - 1) / nrel;

    // ---- CSR build: dst-grouped edges (4B payload), no histogram ----
    hipMemsetAsync(deg, 0, (size_t)NN * sizeof(int), stream);
    hipMemsetAsync(fill, 0, (size_t)NN * sizeof(int), stream);
    deg_kernel<<<2048, 256, 0, stream>>>(dst, deg);
    scan1_kernel<<<SCAN_NB, 256, 0, stream>>>(deg, offs, bsums, NN);
    scan_top_kernel<<<1, 1024, 0, stream>>>(bsums, SCAN_NB);
    scan_add_kernel<<<256, 256, 0, stream>>>(offs, bsums, NN);
    fill_kernel<<<2048, 256, 0, stream>>>(src, dst, et, offs, fill, ep);
    wprep_kernel<<<63, 256, 0, stream>>>(Wh, rooth, Wt);

    // ---- layer 0: fully fused ----
    agg0_kernel<<<2048, 256, 0, stream>>>(
        x, offs, ep, W0, root0, b0, gamma, beta, rmean, rvar, h0);

    // ---- layers 1..3: (128-node, 3-rel)-block transform + aggregate ----
    const int XB = (NN + 127) / 128;   // 391
    for (int l = 1; l < 4; ++l) {
        const unsigned short* hin = (l == 2) ? h1 : h0;
        unsigned short* hout = (l == 1) ? h1 : h0;
        const float* bl  = bh + (size_t)(l - 1) * 64;
        const float* gl  = gamma + (size_t)l * 64;
        const float* btl = beta + (size_t)l * 64;
        const float* rml = rmean + (size_t)l * 64;
        const float* rvl = rvar + (size_t)l * 64;
        int c0 = 0;
        for (int p = 0; p < npass; ++p) {
            int c1 = c0 + nrel; if (c1 > 21) c1 = 21;
            int nr = c1 - c0;
            dim3 xg(XB, (nr + 2) / 3);
            xform_kernel<<<xg, 256, 0, stream>>>(
                hin, Wt + (size_t)(l - 1) * 21 * 4096, T, c0, nr);
            bool first = (p == 0), lastp = (p == npass - 1);
            bool lastl = lastp && (l == 3);
            #define AGG(F, LP, LL) agg_kernel<F, LP, LL><<<2048, 256, 0, stream>>>( \
                T, offs, ep, accum, c0, c1, bl, gl, btl, rml, rvl, hout, out)
            if (first && lastp && lastl)      AGG(true,  true,  true);
            else if (first && lastp)          AGG(true,  true,  false);
            else if (first)                   AGG(true,  false, false);
            else if (lastp && lastl)          AGG(false, true,  true);
            else if (lastp)                   AGG(false, true,  false);
            else                              AGG(false, false, false);
            #undef AGG
            c0 = c1;
        }
    }
}